// Round 1
// baseline (59.315 us; speedup 1.0000x reference)
//
#include <hip/hip_runtime.h>

#define HW   16384   // 128*128
#define WD   128
#define TD   10
#define BD   16
#define NB   32      // 2*B
#define TAUC 100.0f

// ws float layout:
//   A  : [0        , 32*HW)   gathered planes cat[i,:,:,0]  (i<16: x2, i>=16: x1)
//   Y  : [32*HW    , 64*HW)   a + updates
//   U8 : [64*HW    , 80*HW)   u[:, :, :, 8]
//   U9 : [80*HW    , 96*HW)   u[:, :, :, 9]
//   PD2: [96*HW    , 96*HW+1024)   sum (y_i - a_j)^2
//   US2: [96*HW+1024, 96*HW+1280)  sum (u8_i - u9_j)^2

__device__ __forceinline__ float wave_sum(float v) {
    for (int off = 32; off > 0; off >>= 1) v += __shfl_down(v, off, 64);
    return v;
}
__device__ __forceinline__ float wave_min(float v) {
    for (int off = 32; off > 0; off >>= 1) v = fminf(v, __shfl_down(v, off, 64));
    return v;
}

__global__ void k_gather(const float* __restrict__ x1, const float* __restrict__ x2,
                         const float* __restrict__ u, float* __restrict__ ws) {
    float* A  = ws;
    float* U8 = ws + 64 * HW;
    float* U9 = ws + 80 * HW;
    int idx = blockIdx.x * blockDim.x + threadIdx.x;
    const int totalA = NB * HW;      // 524288
    const int totalU = BD * HW;      // 262144
    if (idx < totalA) {
        int i = idx >> 14, p = idx & (HW - 1);
        const float* src = (i < BD) ? x2 : x1;
        int b = i & (BD - 1);
        A[idx] = src[(size_t)(b * HW + p) * TD + 0];
    } else {
        int k = idx - totalA;
        if (k < totalU) {
            size_t base = (size_t)k * TD;
            U8[k] = u[base + 8];
            U9[k] = u[base + 9];
        }
    }
}

__global__ void k_stencil(const float* __restrict__ ws_in, float* __restrict__ Y,
                          const float* __restrict__ vs, const float* __restrict__ dtp,
                          const float* __restrict__ dxp) {
    const float* A = ws_in;
    int i = blockIdx.x;             // 0..31
    int b = i & (BD - 1);
    float c0 = vs[b * 3 + 0];
    float cx = vs[b * 3 + 1];
    float cy = vs[b * 3 + 2];
    float dti = dtp[b];
    float dx = dxp[0];
    float inv_dx2 = 1.0f / (dx * dx);
    float inv_dx  = 1.0f / dx;
    const float* a = A + (size_t)i * HW;
    float* y = Y + (size_t)i * HW;
    for (int p = threadIdx.x; p < HW; p += blockDim.x) {
        int h = p >> 7, w = p & 127;
        float c   = a[p];
        float aw1 = a[(h << 7) | ((w + 1) & 127)];   // w+1
        float awm = a[(h << 7) | ((w - 1) & 127)];   // w-1
        float ah1 = a[(((h + 1) & 127) << 7) | w];   // h+1
        float ahm = a[(((h - 1) & 127) << 7) | w];   // h-1
        float lap  = aw1 + awm + ah1 + ahm - 4.0f * c;
        float diff = c0 * lap * inv_dx2;
        // dw_m = c - a[w+1]; dw_p = c - a[w-1]; dh_p = c - a[h-1]; dh_m = c - a[h+1]
        float xterm = (cx <= 0.0f) ? (-cx * (c - aw1)) : (cx * (c - awm));
        float yterm = (cy >= 0.0f) ? ( cy * (c - ahm)) : (-cy * (c - ah1));
        float adv = -dti * (c * (xterm + yterm)) * inv_dx;
        y[p] = c + adv + diff;
    }
}

__global__ void k_pairs(const float* __restrict__ ws_in, float* __restrict__ ws_out) {
    const float* A  = ws_in;
    const float* Y  = ws_in + 32 * HW;
    const float* U8 = ws_in + 64 * HW;
    const float* U9 = ws_in + 80 * HW;
    float* PD2 = ws_out + 96 * HW;
    float* US2 = ws_out + 96 * HW + 1024;
    int b = blockIdx.x;
    const float *p0, *p1;
    float* out;
    if (b < 1024) {
        int i = b >> 5, j = b & 31;
        p0 = Y + (size_t)i * HW; p1 = A + (size_t)j * HW; out = PD2 + b;
    } else {
        int k = b - 1024;
        int i = k >> 4, j = k & 15;
        p0 = U8 + (size_t)i * HW; p1 = U9 + (size_t)j * HW; out = US2 + k;
    }
    float s = 0.0f;
    for (int p = threadIdx.x; p < HW; p += blockDim.x) {
        float d = p0[p] - p1[p];
        s += d * d;
    }
    s = wave_sum(s);
    __shared__ float red[4];
    int wid = threadIdx.x >> 6, lane = threadIdx.x & 63;
    if (lane == 0) red[wid] = s;
    __syncthreads();
    if (threadIdx.x == 0) out[0] = red[0] + red[1] + red[2] + red[3];
}

__global__ void k_final(const float* __restrict__ ws_in,
                        const float* __restrict__ vs, float* __restrict__ outp) {
    const float* PD2 = ws_in + 96 * HW;
    const float* US2 = ws_in + 96 * HW + 1024;
    int t = threadIdx.x;            // 0..1023
    int i = t >> 5, j = t & 31;
    int bi = i & 15, bj = j & 15;
    float pd = sqrtf(PD2[t]);
    float us = sqrtf(US2[bi * 16 + bj]);
    float S = us - pd; S = S * S;            // sim = (us - pd)^2
    float S2 = S * S;
    // sim_score
    float ti0 = vs[bi * 3 + 0];
    float ti1 = sqrtf(vs[bi * 3 + 1] * vs[bi * 3 + 1] + vs[bi * 3 + 2] * vs[bi * 3 + 2]);
    float tj0 = vs[bj * 3 + 0];
    float tj1 = sqrtf(vs[bj * 3 + 1] * vs[bj * 3 + 1] + vs[bj * 3 + 2] * vs[bj * 3 + 2]);
    float prod = sqrtf(fabsf(ti0 * tj0) + fabsf(ti1 * tj1));
    float nvi = sqrtf(ti0 * ti0 + ti1 * ti1);
    float nvj = sqrtf(tj0 * tj0 + tj1 * tj1);
    float ss = prod / fmaxf(nvi, nvj);

    float pos = 0.5f * ss * S2;
    float om  = 1.0f - ss;

    float sp = wave_sum(pos);
    float so = wave_sum(om);
    float sm = wave_min(S2);
    __shared__ float rs[16], ro[16], rm[16];
    int wid = t >> 6, lane = t & 63;
    if (lane == 0) { rs[wid] = sp; ro[wid] = so; rm[wid] = sm; }
    __syncthreads();
    if (t == 0) {
        float SP = 0.0f, SO = 0.0f, SM = rm[0];
        for (int k = 0; k < 16; ++k) { SP += rs[k]; SO += ro[k]; SM = fminf(SM, rm[k]); }
        float scal = fmaxf(TAUC - SM, 0.0f);
        outp[0] = (SP + 0.5f * SO * scal) * (1.0f / 1024.0f) * (1.0f / 16.0f);
    }
}

extern "C" void kernel_launch(void* const* d_in, const int* in_sizes, int n_in,
                              void* d_out, int out_size, void* d_ws, size_t ws_size,
                              hipStream_t stream) {
    const float* x1 = (const float*)d_in[0];
    const float* x2 = (const float*)d_in[1];
    const float* vs = (const float*)d_in[2];
    const float* u  = (const float*)d_in[3];
    const float* dt = (const float*)d_in[4];
    const float* dx = (const float*)d_in[5];
    float* ws = (float*)d_ws;
    float* out = (float*)d_out;

    // 1) gather t-slices into contiguous ws
    {
        int total = NB * HW + BD * HW;   // 786432
        k_gather<<<(total + 255) / 256, 256, 0, stream>>>(x1, x2, u, ws);
    }
    // 2) stencil -> Y
    k_stencil<<<NB, 256, 0, stream>>>(ws, ws + 32 * HW, vs, dt, dx);
    // 3) pairwise squared distances
    k_pairs<<<1024 + 256, 256, 0, stream>>>(ws, ws);
    // 4) epilogue
    k_final<<<1, 1024, 0, stream>>>(ws, vs, out);
}

// Round 2
// 48.183 us; speedup vs baseline: 1.2310x; 1.2310x over previous
//
#include <hip/hip_runtime.h>

#define HW    16384   // 128*128
#define BD    16
#define NB    32      // 2*B
#define TAUC  100.0f

// ws float layout:
//   A  : [0      , 32*HW)        gathered planes cat[i,:,:,0]  (i<16: x2, i>=16: x1)
//   U8 : [32*HW  , 48*HW)        u[:,:,:,8]
//   U9 : [48*HW  , 64*HW)        u[:,:,:,9]
//   PD : [64*HW  , 64*HW+65536)  partial sum (y_i-a_j)^2, layout [pair(1024)][chunk(64)]
//   US : [+65536 , +16384)       partial sum (u8_i-u9_j)^2, layout [pair(256)][chunk(64)]
#define A_OFF   0
#define U8_OFF  (32*HW)
#define U9_OFF  (48*HW)
#define PD_OFF  (64*HW)
#define US_OFF  (64*HW + 1024*64)

__device__ __forceinline__ float wave_sum(float v) {
    for (int off = 32; off > 0; off >>= 1) v += __shfl_down(v, off, 64);
    return v;
}
__device__ __forceinline__ float wave_min(float v) {
    for (int off = 32; off > 0; off >>= 1) v = fminf(v, __shfl_down(v, off, 64));
    return v;
}

// ---- K1: strided gather of t-slices into contiguous ws (256 blocks) ----
__global__ __launch_bounds__(256) void k_gather(const float* __restrict__ x1,
                                                const float* __restrict__ x2,
                                                const float* __restrict__ u,
                                                float* __restrict__ ws) {
    int tid = threadIdx.x, blk = blockIdx.x;
    float* A  = ws + A_OFF;
    float* U8 = ws + U8_OFF;
    float* U9 = ws + U9_OFF;
    int baseA = blk * 2048;
#pragma unroll
    for (int s = 0; s < 8; ++s) {
        int e = baseA + s * 256 + tid;
        int i = e >> 14, p = e & (HW - 1);
        const float* src = (i < BD) ? x2 : x1;
        int b = i & (BD - 1);
        A[e] = src[(size_t)((b << 14) + p) * 10];
    }
    int baseU = blk * 1024;
#pragma unroll
    for (int s = 0; s < 4; ++s) {
        int k = baseU + s * 256 + tid;
        float2 v = *reinterpret_cast<const float2*>(u + (size_t)k * 10 + 8);
        U8[k] = v.x;
        U9[k] = v.y;
    }
}

// ---- K2: pairwise squared distances, Y computed on the fly (128 blocks) ----
// blocks 0..63 : PD chunk c=blk, k-range [c*256, c*256+256)
// blocks 64..127: US chunk c=blk-64, same k-range
__global__ __launch_bounds__(256) void k_pairs(const float* __restrict__ ws_in,
                                               float* __restrict__ ws_out,
                                               const float* __restrict__ vs,
                                               const float* __restrict__ dtp,
                                               const float* __restrict__ dxp) {
    int tid = threadIdx.x, blk = blockIdx.x;
    if (blk < 64) {
        const float* A = ws_in + A_OFF;
        __shared__ float sY[32][66];
        __shared__ float sA[32][66];
        __shared__ float sc0[32], scx[32], scy[32], sdt[32];
        if (tid < 32) {
            int b = tid & 15;
            sc0[tid] = vs[b * 3 + 0];
            scx[tid] = vs[b * 3 + 1];
            scy[tid] = vs[b * 3 + 2];
            sdt[tid] = dtp[b];
        }
        float dxv = dxp[0];
        float inv_dx = 1.0f / dxv, inv_dx2 = inv_dx * inv_dx;
        __syncthreads();
        int k0 = blk * 256;
        float acc00 = 0.f, acc01 = 0.f, acc10 = 0.f, acc11 = 0.f;
        int ti = tid >> 4, tj = tid & 15;
        for (int sub = 0; sub < 4; ++sub) {
            int kb = k0 + sub * 64;
            // build sA (center values) + sY (center + update) for 32 rows x 64 cols
            for (int e = tid; e < 2048; e += 256) {
                int row = e >> 6, kk = e & 63;
                int p = kb + kk;
                int h = p >> 7, w = p & 127;
                const float* a = A + row * HW;
                float c   = a[p];
                float aw1 = a[(h << 7) | ((w + 1) & 127)];
                float awm = a[(h << 7) | ((w - 1) & 127)];
                float ah1 = a[(((h + 1) & 127) << 7) | w];
                float ahm = a[(((h - 1) & 127) << 7) | w];
                float lap = aw1 + awm + ah1 + ahm - 4.0f * c;
                float cx = scx[row], cy = scy[row];
                float xterm = (cx <= 0.0f) ? (-cx * (c - aw1)) : (cx * (c - awm));
                float yterm = (cy >= 0.0f) ? ( cy * (c - ahm)) : (-cy * (c - ah1));
                float yv = c - sdt[row] * (c * (xterm + yterm)) * inv_dx
                             + sc0[row] * lap * inv_dx2;
                sA[row][kk] = c;
                sY[row][kk] = yv;
            }
            __syncthreads();
#pragma unroll 4
            for (int kk = 0; kk < 64; kk += 2) {
                float2 y0 = *reinterpret_cast<const float2*>(&sY[ti][kk]);
                float2 y1 = *reinterpret_cast<const float2*>(&sY[ti + 16][kk]);
                float2 a0 = *reinterpret_cast<const float2*>(&sA[tj][kk]);
                float2 a1 = *reinterpret_cast<const float2*>(&sA[tj + 16][kk]);
                float d;
                d = y0.x - a0.x; acc00 += d * d;
                d = y0.y - a0.y; acc00 += d * d;
                d = y0.x - a1.x; acc01 += d * d;
                d = y0.y - a1.y; acc01 += d * d;
                d = y1.x - a0.x; acc10 += d * d;
                d = y1.y - a0.y; acc10 += d * d;
                d = y1.x - a1.x; acc11 += d * d;
                d = y1.y - a1.y; acc11 += d * d;
            }
            __syncthreads();
        }
        float* PD = ws_out + PD_OFF;
        PD[(ti * 32 + tj) * 64 + blk]               = acc00;
        PD[(ti * 32 + tj + 16) * 64 + blk]          = acc01;
        PD[((ti + 16) * 32 + tj) * 64 + blk]        = acc10;
        PD[((ti + 16) * 32 + tj + 16) * 64 + blk]   = acc11;
    } else {
        int c = blk - 64;
        int k0 = c * 256;
        int i = tid >> 4, j = tid & 15;
        const float4* p8 = reinterpret_cast<const float4*>(ws_in + U8_OFF + i * HW + k0);
        const float4* p9 = reinterpret_cast<const float4*>(ws_in + U9_OFF + j * HW + k0);
        float acc = 0.f;
#pragma unroll 8
        for (int m = 0; m < 64; ++m) {
            float4 a = p8[m], b = p9[m];
            float d;
            d = a.x - b.x; acc += d * d;
            d = a.y - b.y; acc += d * d;
            d = a.z - b.z; acc += d * d;
            d = a.w - b.w; acc += d * d;
        }
        (ws_out + US_OFF)[(i * 16 + j) * 64 + c] = acc;
    }
}

// ---- K3: fold partials + scalar epilogue (1 block) ----
__global__ __launch_bounds__(256) void k_final(const float* __restrict__ ws,
                                               const float* __restrict__ vs,
                                               float* __restrict__ outp) {
    int tid = threadIdx.x;
    const float4* PD = reinterpret_cast<const float4*>(ws + PD_OFF);
    const float4* US = reinterpret_cast<const float4*>(ws + US_OFF);
    float sum_pos = 0.0f, sum_om = 0.0f, min_s2 = 3.4e38f;
#pragma unroll
    for (int q = 0; q < 4; ++q) {
        int pair = q * 256 + tid;
        int i = pair >> 5, j = pair & 31;
        int bi = i & 15, bj = j & 15;
        float4 av = make_float4(0.f, 0.f, 0.f, 0.f);
#pragma unroll
        for (int m = 0; m < 16; ++m) {
            float4 v = PD[pair * 16 + m];
            av.x += v.x; av.y += v.y; av.z += v.z; av.w += v.w;
        }
        float pd2 = (av.x + av.y) + (av.z + av.w);
        float4 uv = make_float4(0.f, 0.f, 0.f, 0.f);
#pragma unroll
        for (int m = 0; m < 16; ++m) {
            float4 v = US[(bi * 16 + bj) * 16 + m];
            uv.x += v.x; uv.y += v.y; uv.z += v.z; uv.w += v.w;
        }
        float us2 = (uv.x + uv.y) + (uv.z + uv.w);
        float pd = sqrtf(pd2), us = sqrtf(us2);
        float S = us - pd; S = S * S;
        float S2 = S * S;
        float ti0 = vs[bi * 3 + 0];
        float ti1 = sqrtf(vs[bi * 3 + 1] * vs[bi * 3 + 1] + vs[bi * 3 + 2] * vs[bi * 3 + 2]);
        float tj0 = vs[bj * 3 + 0];
        float tj1 = sqrtf(vs[bj * 3 + 1] * vs[bj * 3 + 1] + vs[bj * 3 + 2] * vs[bj * 3 + 2]);
        float prod = sqrtf(fabsf(ti0 * tj0) + fabsf(ti1 * tj1));
        float nvi = sqrtf(ti0 * ti0 + ti1 * ti1);
        float nvj = sqrtf(tj0 * tj0 + tj1 * tj1);
        float ss = prod / fmaxf(nvi, nvj);
        sum_pos += 0.5f * ss * S2;
        sum_om  += 1.0f - ss;
        min_s2 = fminf(min_s2, S2);
    }
    sum_pos = wave_sum(sum_pos);
    sum_om  = wave_sum(sum_om);
    min_s2  = wave_min(min_s2);
    __shared__ float rp[4], ro[4], rm[4];
    int wid = tid >> 6, lane = tid & 63;
    if (lane == 0) { rp[wid] = sum_pos; ro[wid] = sum_om; rm[wid] = min_s2; }
    __syncthreads();
    if (tid == 0) {
        float SP = (rp[0] + rp[1]) + (rp[2] + rp[3]);
        float SO = (ro[0] + ro[1]) + (ro[2] + ro[3]);
        float SM = fminf(fminf(rm[0], rm[1]), fminf(rm[2], rm[3]));
        float scal = fmaxf(TAUC - SM, 0.0f);
        outp[0] = (SP + 0.5f * SO * scal) * (1.0f / 1024.0f) * (1.0f / 16.0f);
    }
}

extern "C" void kernel_launch(void* const* d_in, const int* in_sizes, int n_in,
                              void* d_out, int out_size, void* d_ws, size_t ws_size,
                              hipStream_t stream) {
    const float* x1 = (const float*)d_in[0];
    const float* x2 = (const float*)d_in[1];
    const float* vs = (const float*)d_in[2];
    const float* u  = (const float*)d_in[3];
    const float* dt = (const float*)d_in[4];
    const float* dx = (const float*)d_in[5];
    float* ws  = (float*)d_ws;
    float* out = (float*)d_out;

    k_gather<<<256, 256, 0, stream>>>(x1, x2, u, ws);
    k_pairs <<<128, 256, 0, stream>>>(ws, ws, vs, dt, dx);
    k_final <<<1,   256, 0, stream>>>(ws, vs, out);
}